// Round 4
// baseline (96.098 us; speedup 1.0000x reference)
//
#include <hip/hip_runtime.h>

// DWT (Haar) forward: x (B=8, C=32, H=512, W=512) fp32
//   -> out (B, 4C, H/2, W/2), out channel = 4*c + {A,H,V,D}
//
// Memory-bound streaming: 268 MB in + 268 MB out, zero reuse.
// R4 change: compile-time trip count (exactly 4 iterations/thread, fully
// unrolled) so the compiler interleaves all 16 loads ahead of the stores
// (4x memory-level parallelism vs the runtime grid-stride loop), plus
// 32-bit offsets so loads use the saddr+voffset form.

typedef float f32x4 __attribute__((ext_vector_type(4)));

__device__ __forceinline__ void haar2(const f32x4 r0, const f32x4 r1,
                                      float* A, float* Hh, float* V, float* D) {
    // two column pairs: (x,y) and (z,w)
    {
        const float s0 = r0.x + r0.y, s1 = r1.x + r1.y;
        const float d0 = r0.x - r0.y, d1 = r1.x - r1.y;
        A[0]  = (s0 + s1) * 0.5f;
        Hh[0] = (s0 - s1) * 0.5f;
        V[0]  = (d0 + d1) * 0.5f;
        D[0]  = (d0 - d1) * 0.5f;
    }
    {
        const float s0 = r0.z + r0.w, s1 = r1.z + r1.w;
        const float d0 = r0.z - r0.w, d1 = r1.z - r1.w;
        A[1]  = (s0 + s1) * 0.5f;
        Hh[1] = (s0 - s1) * 0.5f;
        V[1]  = (d0 + d1) * 0.5f;
        D[1]  = (d0 - d1) * 0.5f;
    }
}

__global__ __launch_bounds__(256) void dwt_haar_kernel(
    const float* __restrict__ x, float* __restrict__ out) {
    constexpr int H = 512, W = 512;
    constexpr int h = H / 2, w = W / 2;   // 256, 256
    constexpr int wq = w / 4;             // 64 float4-columns per output row
    constexpr int BC = 8 * 32;            // fused batch*channel = 256
    constexpr int total = BC * h * wq;    // 4,194,304
    constexpr int ITERS = 4;
    constexpr int CHUNK = total / ITERS;  // 1,048,576 = grid*block

    const unsigned base = blockIdx.x * blockDim.x + threadIdx.x;

#pragma unroll
    for (int k = 0; k < ITERS; ++k) {
        const unsigned idx = base + (unsigned)k * CHUNK;
        const unsigned j4 = idx & (wq - 1);         // 0..63  (6 bits)
        const unsigned i  = (idx >> 6) & (h - 1);   // 0..255 (8 bits)
        const unsigned bc = idx >> 14;              // 0..255

        const unsigned in_row0 = (bc * H + 2 * i) * W + 8 * j4;  // < 2^26
        const f32x4 r0a = __builtin_nontemporal_load(
            reinterpret_cast<const f32x4*>(&x[in_row0]));
        const f32x4 r0b = __builtin_nontemporal_load(
            reinterpret_cast<const f32x4*>(&x[in_row0 + 4]));
        const f32x4 r1a = __builtin_nontemporal_load(
            reinterpret_cast<const f32x4*>(&x[in_row0 + W]));
        const f32x4 r1b = __builtin_nontemporal_load(
            reinterpret_cast<const f32x4*>(&x[in_row0 + W + 4]));

        f32x4 cA, cHh, cV, cD;
        {
            float A[2], Hh[2], V[2], D[2];
            haar2(r0a, r1a, A, Hh, V, D);
            cA.x = A[0];  cA.y = A[1];
            cHh.x = Hh[0]; cHh.y = Hh[1];
            cV.x = V[0];  cV.y = V[1];
            cD.x = D[0];  cD.y = D[1];
        }
        {
            float A[2], Hh[2], V[2], D[2];
            haar2(r0b, r1b, A, Hh, V, D);
            cA.z = A[0];  cA.w = A[1];
            cHh.z = Hh[0]; cHh.w = Hh[1];
            cV.z = V[0];  cV.w = V[1];
            cD.z = D[0];  cD.w = D[1];
        }

        const unsigned plane = (unsigned)h * w;  // 65536
        const unsigned obase = (4 * bc * h + i) * w + 4 * j4;  // < 2^26
        __builtin_nontemporal_store(cA,
            reinterpret_cast<f32x4*>(&out[obase]));
        __builtin_nontemporal_store(cHh,
            reinterpret_cast<f32x4*>(&out[obase + plane]));
        __builtin_nontemporal_store(cV,
            reinterpret_cast<f32x4*>(&out[obase + 2 * plane]));
        __builtin_nontemporal_store(cD,
            reinterpret_cast<f32x4*>(&out[obase + 3 * plane]));
    }
}

extern "C" void kernel_launch(void* const* d_in, const int* in_sizes, int n_in,
                              void* d_out, int out_size, void* d_ws, size_t ws_size,
                              hipStream_t stream) {
    const float* x = (const float*)d_in[0];
    float* out = (float*)d_out;

    // grid*block must equal CHUNK = 1,048,576: 4096 blocks x 256 threads.
    // Each thread does exactly ITERS=4 fully-unrolled iterations.
    const int block = 256;
    const int grid = 4096;
    dwt_haar_kernel<<<grid, block, 0, stream>>>(x, out);
}

// Round 5
// 90.301 us; speedup vs baseline: 1.0642x; 1.0642x over previous
//
#include <hip/hip_runtime.h>

// DWT (Haar) forward: x (B=8, C=32, H=512, W=512) fp32
//   -> out (B, 4C, H/2, W/2), out channel = 4*c + {A,H,V,D}
//
// Memory-bound streaming: 268 MB in + 268 MB out, zero reuse.
// R5 change (A/B vs R3): every memory instruction lane-DENSE.
// One wave owns one (bc, i) input row-pair:
//   loads : lane l reads 16B at 4l and 256+4l of rows 2i and 2i+1
//           -> 4x global_load_dwordx4, each a dense 1KB wave segment
//   stores: lane l writes float2 at 2l and 128+2l in each of 4 planes
//           -> 8x global_store_dwordx2, each a dense 512B wave segment
// (Previous layout had 32B lane stride / 16B use on loads.)

typedef float f32x4 __attribute__((ext_vector_type(4)));
typedef float f32x2 __attribute__((ext_vector_type(2)));

__device__ __forceinline__ f32x2 haar_pair(const f32x4 t, const f32x4 b,
                                           int mode01, int mode23) {
    // t = top row cols [4l..4l+4), b = bottom row; two 2x2 blocks:
    // block0 = (t.x t.y / b.x b.y), block1 = (t.z t.w / b.z b.w)
    // mode: 0=A (+ +), 1=H (+ -), 2=V (- +), 3=D (- -)
    // coeff = 0.5 * (colop(t) rowop colop(b)), colop = +/- per mode bit1,
    // rowop per mode bit0... expanded explicitly by caller instead.
    (void)mode01; (void)mode23;
    return f32x2{0.f, 0.f};
}

__global__ __launch_bounds__(256) void dwt_haar_kernel(
    const float* __restrict__ x, float* __restrict__ out) {
    constexpr int H = 512, W = 512;
    constexpr int h = H / 2, w = W / 2;     // 256, 256
    constexpr int BC = 8 * 32;              // 256
    constexpr unsigned total = (unsigned)BC * h * 64;  // 64 lanes/row-pair = 4,194,304

    const unsigned stride = gridDim.x * blockDim.x;
    for (unsigned idx = blockIdx.x * blockDim.x + threadIdx.x;
         idx < total; idx += stride) {
        const unsigned l   = idx & 63;          // lane within row-pair
        const unsigned wid = idx >> 6;
        const unsigned i   = wid & (h - 1);     // 0..255
        const unsigned bc  = wid >> 8;          // 0..255

        const unsigned in_base = (bc * H + 2 * i) * W;  // < 2^26
        // dense loads: seg0 at 4l, seg1 at 256+4l, both rows
        const f32x4 t0 = __builtin_nontemporal_load(
            reinterpret_cast<const f32x4*>(&x[in_base + 4 * l]));
        const f32x4 t1 = __builtin_nontemporal_load(
            reinterpret_cast<const f32x4*>(&x[in_base + 256 + 4 * l]));
        const f32x4 b0 = __builtin_nontemporal_load(
            reinterpret_cast<const f32x4*>(&x[in_base + W + 4 * l]));
        const f32x4 b1 = __builtin_nontemporal_load(
            reinterpret_cast<const f32x4*>(&x[in_base + W + 256 + 4 * l]));

        // seg0: output cols 2l, 2l+1 ; seg1: output cols 128+2l, 128+2l+1
        f32x2 A0, H0, V0, D0, A1, H1, V1, D1;
        {
            const float s0 = t0.x + t0.y, s1 = b0.x + b0.y;
            const float d0 = t0.x - t0.y, d1 = b0.x - b0.y;
            A0.x = (s0 + s1) * 0.5f;  H0.x = (s0 - s1) * 0.5f;
            V0.x = (d0 + d1) * 0.5f;  D0.x = (d0 - d1) * 0.5f;
        }
        {
            const float s0 = t0.z + t0.w, s1 = b0.z + b0.w;
            const float d0 = t0.z - t0.w, d1 = b0.z - b0.w;
            A0.y = (s0 + s1) * 0.5f;  H0.y = (s0 - s1) * 0.5f;
            V0.y = (d0 + d1) * 0.5f;  D0.y = (d0 - d1) * 0.5f;
        }
        {
            const float s0 = t1.x + t1.y, s1 = b1.x + b1.y;
            const float d0 = t1.x - t1.y, d1 = b1.x - b1.y;
            A1.x = (s0 + s1) * 0.5f;  H1.x = (s0 - s1) * 0.5f;
            V1.x = (d0 + d1) * 0.5f;  D1.x = (d0 - d1) * 0.5f;
        }
        {
            const float s0 = t1.z + t1.w, s1 = b1.z + b1.w;
            const float d0 = t1.z - t1.w, d1 = b1.z - b1.w;
            A1.y = (s0 + s1) * 0.5f;  H1.y = (s0 - s1) * 0.5f;
            V1.y = (d0 + d1) * 0.5f;  D1.y = (d0 - d1) * 0.5f;
        }

        constexpr unsigned plane = (unsigned)h * w;          // 65536
        const unsigned obase = (4 * bc * h + i) * w;         // < 2^26
        float* o0 = &out[obase + 2 * l];
        float* o1 = &out[obase + 128 + 2 * l];
        __builtin_nontemporal_store(A0, reinterpret_cast<f32x2*>(o0));
        __builtin_nontemporal_store(A1, reinterpret_cast<f32x2*>(o1));
        __builtin_nontemporal_store(H0, reinterpret_cast<f32x2*>(o0 + plane));
        __builtin_nontemporal_store(H1, reinterpret_cast<f32x2*>(o1 + plane));
        __builtin_nontemporal_store(V0, reinterpret_cast<f32x2*>(o0 + 2 * plane));
        __builtin_nontemporal_store(V1, reinterpret_cast<f32x2*>(o1 + 2 * plane));
        __builtin_nontemporal_store(D0, reinterpret_cast<f32x2*>(o0 + 3 * plane));
        __builtin_nontemporal_store(D1, reinterpret_cast<f32x2*>(o1 + 3 * plane));
    }
}

extern "C" void kernel_launch(void* const* d_in, const int* in_sizes, int n_in,
                              void* d_out, int out_size, void* d_ws, size_t ws_size,
                              hipStream_t stream) {
    const float* x = (const float*)d_in[0];
    float* out = (float*)d_out;

    // total threads needed: 4,194,304; 2048 blocks x 256 -> 8 grid-stride iters.
    const int block = 256;
    const int grid = 2048;
    dwt_haar_kernel<<<grid, block, 0, stream>>>(x, out);
}